// Round 6
// baseline (288.111 us; speedup 1.0000x reference)
//
#include <hip/hip_runtime.h>
#include <hip/hip_bf16.h>
#include <hip/hip_cooperative_groups.h>

namespace cg = cooperative_groups;

// N=10000 nodes, F=256, H=256, E=320000 edges.
//
// W1 = [W1a | W1b]:  U' = x @ W1a^T + b1 (bias folded), V = x @ W1b^T
// out[e] = sigmoid(b2 + sum_j relu(U'[row][j] + V[col][j]) * W2[j])
// uv layout: uv[node][0:256]=U', uv[node][256:512]=V, bf16 (1 KB/row).
//
// R6: single cooperative kernel (convert -> sync -> gemm -> sync -> edge).
// Kills 2 launch gaps; edge phase pair-pipelined (8 edges / wave-iter,
// 8x16B loads in flight) to cover L2/L3 gather latency at 16 waves/CU.
// Harness tax (unremovable): ~45us 268MB d_ws re-poison fill per window.

typedef __attribute__((ext_vector_type(8))) short bf16x8;
typedef __attribute__((ext_vector_type(4))) float f32x4;

__device__ __forceinline__ unsigned short f2bf(float f) {
    __hip_bfloat16 h = __float2bfloat16(f);
    return *reinterpret_cast<unsigned short*>(&h);
}

__global__ __launch_bounds__(256, 4) void fused_kernel(
        const float* __restrict__ x, const int* __restrict__ ei,
        const float* __restrict__ W1, const float* __restrict__ b1,
        const float* __restrict__ w2, const float* __restrict__ b2p,
        float* __restrict__ out, unsigned short* __restrict__ uv,
        unsigned short* __restrict__ wb, int M, int E) {
    __shared__ __align__(16) unsigned short As[2][16][40];

    cg::grid_group grid = cg::this_grid();
    const int t   = threadIdx.x;
    const int gid = blockIdx.x * 256 + t;

    // ---------------- Phase 0: W1 fp32 -> bf16 (512 KB, ~1.5us) -----------
    if (gid < 32768) {
        float4 v = ((const float4*)W1)[gid];
        ushort4 o = {f2bf(v.x), f2bf(v.y), f2bf(v.z), f2bf(v.w)};
        ((ushort4*)wb)[gid] = o;
    }
    grid.sync();

    // ---------------- Phase 1: gemm (R5 body, grid-stride over m-tiles) ---
    // Block = 16 rows x 512 cols; wave w owns cols w*128..+127.
    // A staged fp32->bf16 in LDS (dbuf, stride 40: 2-way bank alias = free);
    // B streamed 16B/lane from L2-resident wb. C/D: col=lane&15,
    // row=(lane>>4)*4+reg. b1 folded into U half at epilogue.
    const int wave = t >> 6;
    const int lane = t & 63;
    const int lm   = lane & 15;
    const int lq   = lane >> 4;
    const int lk   = lq * 8;
    const int srow = t >> 4;
    const int sk   = (t & 15) * 2;
    const int half    = wave >> 1;
    const int colbase = wave * 128;
    const int rowbase = (wave & 1) * 128;
    const unsigned short* bpre =
        wb + (size_t)(rowbase + lm) * 512 + half * 256 + lk;

    const int ntiles = (M + 15) / 16;
    for (int mt = blockIdx.x; mt < ntiles; mt += gridDim.x) {
        const int m0   = mt * 16;
        const int grow = m0 + srow;
        const float* sptr = x + (size_t)(grow < M ? grow : (M - 1)) * 256 + sk;

        f32x4 acc[8];
#pragma unroll
        for (int j = 0; j < 8; ++j) acc[j] = f32x4{0.f, 0.f, 0.f, 0.f};

        float2 apref = *(const float2*)(sptr);

#pragma unroll
        for (int it = 0; it < 8; ++it) {
            const int kt  = it * 32;
            const int cur = it & 1;
            unsigned int lo = ((unsigned int)f2bf(apref.x));
            unsigned int hi = ((unsigned int)f2bf(apref.y)) << 16;
            *(unsigned int*)&As[cur][srow][sk] = lo | hi;
            if (it < 7) apref = *(const float2*)(sptr + kt + 32);
            __syncthreads();
            bf16x8 a = *(const bf16x8*)&As[cur][lm][lk];
#pragma unroll
            for (int j = 0; j < 8; ++j) {
                bf16x8 b = *(const bf16x8*)(bpre + (size_t)j * 16 * 512 + kt);
                acc[j] = __builtin_amdgcn_mfma_f32_16x16x32_bf16(a, b, acc[j], 0, 0, 0);
            }
        }

        const int row0 = m0 + lq * 4;
#pragma unroll
        for (int j = 0; j < 8; ++j) {
            const int col  = colbase + j * 16 + lm;
            const float badd = half ? 0.f : b1[col];
#pragma unroll
            for (int r = 0; r < 4; ++r) {
                if (row0 + r < M)
                    uv[(size_t)(row0 + r) * 512 + col] = f2bf(acc[j][r] + badd);
            }
        }
        __syncthreads();   // As reuse guard across tiles
    }
    grid.sync();

    // ---------------- Phase 2: edge, pair-pipelined -----------------------
    // 4 edges/wave-batch (g=lane>>4 edge slot, c=lane&15 col chunk, 32B/lane
    // per row). Two independent batches per iteration: all 8x16B loads
    // issued before compute -> 2x vmem in flight vs R5.
    const int g = lq;
    const int c = lm;
    const int wid  = blockIdx.x * 4 + wave;
    const int nwav = gridDim.x * 4;
    const int nb   = E >> 2;

    float w2r[16];
#pragma unroll
    for (int i = 0; i < 4; ++i)
        *(float4*)&w2r[i * 4] = *(const float4*)(w2 + c * 16 + i * 4);
    const float b2 = b2p[0];

    for (int b = wid; b < nb; b += 2 * nwav) {
        const int bB = b + nwav;
        const bool has2 = bB < nb;

        const int e0 = b * 4 + g;
        const int r0 = ei[e0];
        const int c0 = ei[E + e0];
        const int e1 = has2 ? bB * 4 + g : e0;
        const int r1 = ei[e1];
        const int c1 = ei[E + e1];

        const uint4* up0 = (const uint4*)(uv + (size_t)r0 * 512 + c * 16);
        const uint4* vp0 = (const uint4*)(uv + (size_t)c0 * 512 + 256 + c * 16);
        const uint4* up1 = (const uint4*)(uv + (size_t)r1 * 512 + c * 16);
        const uint4* vp1 = (const uint4*)(uv + (size_t)c1 * 512 + 256 + c * 16);

        uint4 ua0 = up0[0], ua1 = up0[1];
        uint4 va0 = vp0[0], va1 = vp0[1];
        uint4 ub0 = up1[0], ub1 = up1[1];
        uint4 vb0 = vp1[0], vb1 = vp1[1];

        unsigned int uw[8], vw[8];
        float2 p2;
        float p;

        // ---- batch A ----
        *(uint4*)&uw[0] = ua0; *(uint4*)&uw[4] = ua1;
        *(uint4*)&vw[0] = va0; *(uint4*)&vw[4] = va1;
        p2 = float2{0.f, 0.f};
#pragma unroll
        for (int i = 0; i < 8; ++i) {
            float2 u2 = {__uint_as_float(uw[i] << 16),
                         __uint_as_float(uw[i] & 0xffff0000u)};
            float2 v2 = {__uint_as_float(vw[i] << 16),
                         __uint_as_float(vw[i] & 0xffff0000u)};
            float2 s2 = {fmaxf(u2.x + v2.x, 0.f), fmaxf(u2.y + v2.y, 0.f)};
            p2.x = fmaf(s2.x, w2r[2 * i], p2.x);
            p2.y = fmaf(s2.y, w2r[2 * i + 1], p2.y);
        }
        p = p2.x + p2.y;
#pragma unroll
        for (int off = 1; off < 16; off <<= 1)
            p += __shfl_xor(p, off, 64);
        if (c == 0) out[e0] = 1.f / (1.f + __expf(-(p + b2)));

        // ---- batch B ----
        if (has2) {
            *(uint4*)&uw[0] = ub0; *(uint4*)&uw[4] = ub1;
            *(uint4*)&vw[0] = vb0; *(uint4*)&vw[4] = vb1;
            p2 = float2{0.f, 0.f};
#pragma unroll
            for (int i = 0; i < 8; ++i) {
                float2 u2 = {__uint_as_float(uw[i] << 16),
                             __uint_as_float(uw[i] & 0xffff0000u)};
                float2 v2 = {__uint_as_float(vw[i] << 16),
                             __uint_as_float(vw[i] & 0xffff0000u)};
                float2 s2 = {fmaxf(u2.x + v2.x, 0.f), fmaxf(u2.y + v2.y, 0.f)};
                p2.x = fmaf(s2.x, w2r[2 * i], p2.x);
                p2.y = fmaf(s2.y, w2r[2 * i + 1], p2.y);
            }
            p = p2.x + p2.y;
#pragma unroll
            for (int off = 1; off < 16; off <<= 1)
                p += __shfl_xor(p, off, 64);
            if (c == 0) out[e1] = 1.f / (1.f + __expf(-(p + b2)));
        }
    }
}

extern "C" void kernel_launch(void* const* d_in, const int* in_sizes, int n_in,
                              void* d_out, int out_size, void* d_ws, size_t ws_size,
                              hipStream_t stream) {
    const float* x  = (const float*)d_in[0];
    const int*   ei = (const int*)d_in[1];
    const float* W1 = (const float*)d_in[2];
    const float* b1 = (const float*)d_in[3];
    const float* W2 = (const float*)d_in[4];
    const float* b2 = (const float*)d_in[5];
    float* out = (float*)d_out;

    int N = in_sizes[0] / 256;   // 10000
    int E = in_sizes[1] / 2;     // 320000

    unsigned short* uv = (unsigned short*)d_ws;        // N*512 bf16 (10.24 MB)
    unsigned short* wb = uv + (size_t)N * 512;         // 256*512 bf16 (256 KB)

    // Cooperative grid: co-residency required. Occupancy query is host-side
    // and deterministic (capture-safe).
    int maxBlk = 0;
    hipOccupancyMaxActiveBlocksPerMultiprocessor(&maxBlk, (const void*)fused_kernel,
                                                 256, 0);
    if (maxBlk < 1) maxBlk = 1;
    if (maxBlk > 8) maxBlk = 8;
    int grid = maxBlk * 256;

    void* args[] = {(void*)&x, (void*)&ei, (void*)&W1, (void*)&b1, (void*)&W2,
                    (void*)&b2, (void*)&out, (void*)&uv, (void*)&wb,
                    (void*)&N, (void*)&E};
    hipLaunchCooperativeKernel((void*)fused_kernel, dim3(grid), dim3(256),
                               args, 0, stream);
}

// Round 7
// 130.512 us; speedup vs baseline: 2.2075x; 2.2075x over previous
//
#include <hip/hip_runtime.h>
#include <hip/hip_bf16.h>

// N=10000 nodes, F=256, H=256, E=320000 edges.
//
// W1 = [W1a | W1b]:  U' = x @ W1a^T + b1 (bias folded), V = x @ W1b^T
// out[e] = sigmoid(b2 + sum_j relu(U'[row][j] + V[col][j]) * W2[j])
// uv layout: uv[node][0:256]=U', uv[node][256:512]=V, bf16 (1 KB/row).
//
// R6 lesson: fusing all phases into one cooperative kernel shared one
// register allocation -> spills (WRITE_SIZE 10->54 MB, 288us). Keep phases
// as separate kernels with independent register budgets.
// Harness tax (unremovable): ~45us 268MB d_ws re-poison fill per window
// plus small restore memsets.

typedef __attribute__((ext_vector_type(8))) short bf16x8;
typedef __attribute__((ext_vector_type(4))) float f32x4;

__device__ __forceinline__ unsigned short f2bf(float f) {
    __hip_bfloat16 h = __float2bfloat16(f);
    return *reinterpret_cast<unsigned short*>(&h);
}

// ---------------------------------------------------------------------------
// Kernel 0: convert W1 (256x512 fp32) to bf16. Tiny (~2us).
// ---------------------------------------------------------------------------
__global__ __launch_bounds__(256) void convert_w(const float* __restrict__ w1,
                                                 unsigned short* __restrict__ wb,
                                                 int nw4) {
    int i = blockIdx.x * 256 + threadIdx.x;
    if (i < nw4) {
        float4 v = ((const float4*)w1)[i];
        ushort4 o = {f2bf(v.x), f2bf(v.y), f2bf(v.z), f2bf(v.w)};
        ((ushort4*)wb)[i] = o;
    }
}

// ---------------------------------------------------------------------------
// Kernel 1 (R5, proven): block = 16 rows x 512 cols. Wave w owns cols
// w*128..+127 (8 n-tiles). Per ktile (K=32): stage A (16x32 fp32->bf16)
// into dbuf LDS (stride 40: 2-way bank alias = free); 1 ds_read_b128 A-frag
// + 8x 16B B-frags from L2-resident wb + 8 MFMA 16x16x32.
// C/D: col=lane&15, row=(lane>>4)*4+reg. b1 folded into U half.
// ---------------------------------------------------------------------------
__global__ __launch_bounds__(256) void gemm_mfma(const float* __restrict__ x,
                                                 const unsigned short* __restrict__ wb,
                                                 const float* __restrict__ b1,
                                                 unsigned short* __restrict__ uv,
                                                 int M) {
    __shared__ __align__(16) unsigned short As[2][16][40];

    const int t    = threadIdx.x;
    const int wave = t >> 6;
    const int lane = t & 63;
    const int lm   = lane & 15;
    const int lq   = lane >> 4;
    const int lk   = lq * 8;
    const int m0   = blockIdx.x * 16;

    const int srow = t >> 4;
    const int sk   = (t & 15) * 2;
    const int grow = m0 + srow;
    const float* sptr = x + (size_t)(grow < M ? grow : (M - 1)) * 256 + sk;

    const int half    = wave >> 1;
    const int colbase = wave * 128;
    const int rowbase = (wave & 1) * 128;
    const unsigned short* bpre =
        wb + (size_t)(rowbase + lm) * 512 + half * 256 + lk;

    f32x4 acc[8];
#pragma unroll
    for (int j = 0; j < 8; ++j) acc[j] = f32x4{0.f, 0.f, 0.f, 0.f};

    float2 apref = *(const float2*)(sptr);

#pragma unroll
    for (int it = 0; it < 8; ++it) {
        const int kt  = it * 32;
        const int cur = it & 1;
        unsigned int lo = ((unsigned int)f2bf(apref.x));
        unsigned int hi = ((unsigned int)f2bf(apref.y)) << 16;
        *(unsigned int*)&As[cur][srow][sk] = lo | hi;
        if (it < 7) apref = *(const float2*)(sptr + kt + 32);
        __syncthreads();
        bf16x8 a = *(const bf16x8*)&As[cur][lm][lk];
#pragma unroll
        for (int j = 0; j < 8; ++j) {
            bf16x8 b = *(const bf16x8*)(bpre + (size_t)j * 16 * 512 + kt);
            acc[j] = __builtin_amdgcn_mfma_f32_16x16x32_bf16(a, b, acc[j], 0, 0, 0);
        }
    }

    const int row0 = m0 + lq * 4;
#pragma unroll
    for (int j = 0; j < 8; ++j) {
        const int col  = colbase + j * 16 + lm;
        const float badd = half ? 0.f : b1[col];
#pragma unroll
        for (int r = 0; r < 4; ++r) {
            if (row0 + r < M)
                uv[(size_t)(row0 + r) * 512 + col] = f2bf(acc[j][r] + badd);
        }
    }
}

// ---------------------------------------------------------------------------
// Kernel 2: pair-pipelined edge phase (standalone => own register budget,
// ~100 VGPR, no spill). 4 edges per batch (g=lane>>4 slot, c=lane&15 col
// chunk, 32B/lane per row); TWO independent batches per iteration with all
// 8x16B gather loads issued before any compute (2x vmem in flight vs R5).
// ---------------------------------------------------------------------------
__global__ __launch_bounds__(256) void edge_kernel(const unsigned short* __restrict__ uv,
                                                   const int* __restrict__ ei,
                                                   const float* __restrict__ w2,
                                                   const float* __restrict__ b2p,
                                                   float* __restrict__ out, int E) {
    const int lane = threadIdx.x & 63;
    const int g = lane >> 4;
    const int c = lane & 15;
    const int wid  = (blockIdx.x * blockDim.x + threadIdx.x) >> 6;
    const int nwav = (gridDim.x * blockDim.x) >> 6;
    const int nb   = E >> 2;

    float w2r[16];
#pragma unroll
    for (int i = 0; i < 4; ++i)
        *(float4*)&w2r[i * 4] = *(const float4*)(w2 + c * 16 + i * 4);
    const float b2 = b2p[0];

    for (int b = wid; b < nb; b += 2 * nwav) {
        const int bB = b + nwav;
        const bool has2 = bB < nb;

        const int e0 = b * 4 + g;
        const int r0 = ei[e0];
        const int c0 = ei[E + e0];
        const int e1 = has2 ? bB * 4 + g : e0;
        const int r1 = ei[e1];
        const int c1 = ei[E + e1];

        const uint4* up0 = (const uint4*)(uv + (size_t)r0 * 512 + c * 16);
        const uint4* vp0 = (const uint4*)(uv + (size_t)c0 * 512 + 256 + c * 16);
        const uint4* up1 = (const uint4*)(uv + (size_t)r1 * 512 + c * 16);
        const uint4* vp1 = (const uint4*)(uv + (size_t)c1 * 512 + 256 + c * 16);

        // issue all 8 gather loads before any compute
        uint4 ua0 = up0[0], ua1 = up0[1];
        uint4 va0 = vp0[0], va1 = vp0[1];
        uint4 ub0 = up1[0], ub1 = up1[1];
        uint4 vb0 = vp1[0], vb1 = vp1[1];

        unsigned int uw[8], vw[8];
        float2 p2;
        float p;

        // ---- batch A ----
        *(uint4*)&uw[0] = ua0; *(uint4*)&uw[4] = ua1;
        *(uint4*)&vw[0] = va0; *(uint4*)&vw[4] = va1;
        p2 = float2{0.f, 0.f};
#pragma unroll
        for (int i = 0; i < 8; ++i) {
            float2 u2 = {__uint_as_float(uw[i] << 16),
                         __uint_as_float(uw[i] & 0xffff0000u)};
            float2 v2 = {__uint_as_float(vw[i] << 16),
                         __uint_as_float(vw[i] & 0xffff0000u)};
            float2 s2 = {fmaxf(u2.x + v2.x, 0.f), fmaxf(u2.y + v2.y, 0.f)};
            p2.x = fmaf(s2.x, w2r[2 * i], p2.x);
            p2.y = fmaf(s2.y, w2r[2 * i + 1], p2.y);
        }
        p = p2.x + p2.y;
#pragma unroll
        for (int off = 1; off < 16; off <<= 1)
            p += __shfl_xor(p, off, 64);
        if (c == 0) out[e0] = 1.f / (1.f + __expf(-(p + b2)));

        // ---- batch B ----
        if (has2) {
            *(uint4*)&uw[0] = ub0; *(uint4*)&uw[4] = ub1;
            *(uint4*)&vw[0] = vb0; *(uint4*)&vw[4] = vb1;
            p2 = float2{0.f, 0.f};
#pragma unroll
            for (int i = 0; i < 8; ++i) {
                float2 u2 = {__uint_as_float(uw[i] << 16),
                             __uint_as_float(uw[i] & 0xffff0000u)};
                float2 v2 = {__uint_as_float(vw[i] << 16),
                             __uint_as_float(vw[i] & 0xffff0000u)};
                float2 s2 = {fmaxf(u2.x + v2.x, 0.f), fmaxf(u2.y + v2.y, 0.f)};
                p2.x = fmaf(s2.x, w2r[2 * i], p2.x);
                p2.y = fmaf(s2.y, w2r[2 * i + 1], p2.y);
            }
            p = p2.x + p2.y;
#pragma unroll
            for (int off = 1; off < 16; off <<= 1)
                p += __shfl_xor(p, off, 64);
            if (c == 0) out[e1] = 1.f / (1.f + __expf(-(p + b2)));
        }
    }
}

extern "C" void kernel_launch(void* const* d_in, const int* in_sizes, int n_in,
                              void* d_out, int out_size, void* d_ws, size_t ws_size,
                              hipStream_t stream) {
    const float* x  = (const float*)d_in[0];
    const int*   ei = (const int*)d_in[1];
    const float* W1 = (const float*)d_in[2];
    const float* b1 = (const float*)d_in[3];
    const float* W2 = (const float*)d_in[4];
    const float* b2 = (const float*)d_in[5];
    float* out = (float*)d_out;

    const int N = in_sizes[0] / 256;   // 10000
    const int E = in_sizes[1] / 2;     // 320000

    unsigned short* uv = (unsigned short*)d_ws;        // N*512 bf16 (10.24 MB)
    unsigned short* wb = uv + (size_t)N * 512;         // 256*512 bf16 (256 KB)

    const int nw4 = (256 * 512) / 4;
    convert_w<<<(nw4 + 255) / 256, 256, 0, stream>>>(W1, wb, nw4);

    gemm_mfma<<<(N + 15) / 16, 256, 0, stream>>>(x, wb, b1, uv, N);

    edge_kernel<<<2048, 256, 0, stream>>>(uv, ei, W2, b2, out, E);
}